// Round 10
// baseline (243.456 us; speedup 1.0000x reference)
//
#include <hip/hip_runtime.h>
#include <hip/hip_bf16.h>

#define N_TOK 343
#define N_PAD 344
#define J_PAD 352
#define C_DIM 96
#define H_HEADS 24
#define HD 4
#define B_WIN 32
#define LOG2E 1.4426950408889634f
#define SCALE_Q (0.5f * LOG2E)    // attn scale folded with log2(e) for exp2-space softmax
#define EPS_IN 1e-5f
#define CH_STR (HD * N_PAD)                    // 1376 floats per (b,h)
#define AP ((size_t)B_WIN * H_HEADS * CH_STR)  // 1,056,768 floats per slot
#define BT_ELEMS ((size_t)H_HEADS * N_TOK * N_PAD)     // 2,831,808 floats (11.3 MB)
// layout of q/k/v/vf slots: [b][h][n][d] (float4 per token n)
// ws slots: 0=q1 1=k1 2=q2 3=k2 4=v1(->AO) 5=v2 6=vf [7: biasT if ws_size allows]

typedef float v2f __attribute__((ext_vector_type(2)));
#define FMA2(a, b, c) __builtin_elementwise_fma(a, b, c)

// ---------------- kernel 0: transposed bias: bT[h][j][i] = rpb[rel[i,j]*H+h]*log2e ----------------
__global__ __launch_bounds__(256) void biasT_kernel(const float* __restrict__ rpb,
                                                    const int* __restrict__ rel,
                                                    float* __restrict__ bT) {
    const int h = blockIdx.y;
    const int ti = blockIdx.x / 11, tj = blockIdx.x - 11 * (blockIdx.x / 11);
    const int i0 = ti * 32, j0 = tj * 32;
    __shared__ float tile[32][33];
    const int tid = threadIdx.x;
    for (int e = tid; e < 1024; e += 256) {
        int r = e >> 5, c = e & 31;            // r=i-local, c=j-local (coalesced over j)
        int i = i0 + r, j = j0 + c;
        float v = -16384.f;                    // pad rows: exp2 -> 0
        if (i < N_TOK && j < N_TOK) v = rpb[rel[i * N_TOK + j] * H_HEADS + h] * LOG2E;
        tile[r][c] = v;
    }
    __syncthreads();
    for (int e = tid; e < 1024; e += 256) {
        int c = e >> 5, r = e & 31;            // writes coalesced over i
        int i = i0 + r, j = j0 + c;
        if (i < N_PAD && j < N_TOK)            // also fill i=343 pad with -16384
            bT[((size_t)h * N_TOK + j) * N_PAD + i] = tile[r][c];
    }
}

// ---------------- kernel 1: QKV projection, LDS-tiled GEMM ----------------
__global__ __launch_bounds__(192) void qkv_kernel(const float* __restrict__ x1,
                                                  const float* __restrict__ x2,
                                                  const float* __restrict__ w,
                                                  const float* __restrict__ bqkv,
                                                  float* __restrict__ ws) {
    __shared__ float wt[96 * 100];
    __shared__ float xs[2][32 * 97];
    const int s = blockIdx.y, b = blockIdx.z, r0 = blockIdx.x * 32;
    const int rows = min(32, N_TOK - r0);
    const int tid = threadIdx.x;
    for (int e = tid; e < 96 * 96; e += 192) {
        int j = e / 96, k = e - j * 96;
        wt[k * 100 + j] = w[s * 96 * 96 + e];
    }
    const float* x1p = x1 + ((size_t)b * N_TOK + r0) * C_DIM;
    const float* x2p = x2 + ((size_t)b * N_TOK + r0) * C_DIM;
    for (int e = tid; e < rows * 96; e += 192) {
        int r = e / 96, k = e - r * 96;
        xs[0][r * 97 + k] = x1p[e];
        xs[1][r * 97 + k] = x2p[e];
    }
    __syncthreads();
    const int rg = tid & 7, og = tid >> 3;   // og = head (0..23), rg = row group (0..7)
    const int oc0 = og * 4, rr = rg * 4;
    float acc[2][4][4];
    #pragma unroll
    for (int i = 0; i < 4; ++i) {
        float bv = bqkv[s * 96 + oc0 + i];
        #pragma unroll
        for (int src = 0; src < 2; ++src)
            #pragma unroll
            for (int j = 0; j < 4; ++j) acc[src][i][j] = bv;
    }
    for (int k = 0; k < 96; ++k) {
        float4 w4 = *(const float4*)&wt[k * 100 + oc0];
        float wv[4] = {w4.x, w4.y, w4.z, w4.w};
        float xv0[4], xv1[4];
        #pragma unroll
        for (int j = 0; j < 4; ++j) {
            xv0[j] = xs[0][(rr + j) * 97 + k];
            xv1[j] = xs[1][(rr + j) * 97 + k];
        }
        #pragma unroll
        for (int i = 0; i < 4; ++i)
            #pragma unroll
            for (int j = 0; j < 4; ++j) {
                acc[0][i][j] += xv0[j] * wv[i];
                acc[1][i][j] += xv1[j] * wv[i];
            }
    }
    const float scl = (s == 0) ? SCALE_Q : 1.0f;
    // store layout: [b][h=og][row][d], float4 per row; acc[src][d][j] (oc = og*4+d)
    #pragma unroll
    for (int j = 0; j < 4; ++j) {
        int row = r0 + rr + j;
        if (row >= N_TOK) continue;
        size_t base = (((size_t)b * H_HEADS + og) * N_PAD + row) * 4;
        #pragma unroll
        for (int src = 0; src < 2; ++src) {
            int slot = (s == 0) ? (src ? 2 : 0) : (s == 1) ? (src ? 3 : 1) : (src ? 5 : 4);
            *(float4*)(ws + (size_t)slot * AP + base) =
                make_float4(acc[src][0][j] * scl, acc[src][1][j] * scl,
                            acc[src][2][j] * scl, acc[src][3][j] * scl);
        }
    }
}

// ---------------- kernel 2: fuse (1x1 conv 48->24 + InstanceNorm + relu + sigmoid) ----------------
__global__ __launch_bounds__(256) void fuse_kernel(const float* __restrict__ v1,
                                                   const float* __restrict__ v2,
                                                   const float* __restrict__ fw,
                                                   const float* __restrict__ fb,
                                                   float* __restrict__ vf) {
    const int o = blockIdx.x, b = blockIdx.y;
    __shared__ float ts[N_TOK * HD];
    __shared__ float red[32];
    __shared__ float fwl[48];
    if (threadIdx.x < 48) fwl[threadIdx.x] = fw[o * 48 + threadIdx.x];
    __syncthreads();
    const float bo = fb[o];
    const float* p1 = v1 + (size_t)b * H_HEADS * CH_STR;
    const float* p2 = v2 + (size_t)b * H_HEADS * CH_STR;
    float lsum = 0.f, lsq = 0.f;
    for (int e = threadIdx.x; e < N_TOK * HD; e += blockDim.x) {
        float acc = bo;                        // e = n*4+d matches [n][d] layout directly
        #pragma unroll
        for (int c = 0; c < H_HEADS; ++c) {
            acc += fwl[c]      * p1[(size_t)c * CH_STR + e];
            acc += fwl[24 + c] * p2[(size_t)c * CH_STR + e];
        }
        ts[e] = acc;
        lsum += acc; lsq += acc * acc;
    }
    for (int off = 32; off; off >>= 1) {
        lsum += __shfl_xor(lsum, off);
        lsq  += __shfl_xor(lsq, off);
    }
    int wid = threadIdx.x >> 6, lane = threadIdx.x & 63;
    if (lane == 0) { red[wid] = lsum; red[8 + wid] = lsq; }
    __syncthreads();
    if (threadIdx.x == 0) {
        float su = red[0] + red[1] + red[2] + red[3];
        float q  = red[8] + red[9] + red[10] + red[11];
        float mean = su / (float)(N_TOK * HD);
        float var  = q / (float)(N_TOK * HD) - mean * mean;
        red[16] = mean;
        red[17] = rsqrtf(var + EPS_IN);
    }
    __syncthreads();
    const float mean = red[16], inv = red[17];
    float* outp = vf + ((size_t)b * H_HEADS + o) * CH_STR;
    for (int e = threadIdx.x; e < N_TOK * HD; e += blockDim.x) {
        float x = (ts[e] - mean) * inv;
        x = fmaxf(x, 0.f);
        outp[e] = 1.f / (1.f + __expf(-x));
    }
}

// ---------------- kernel 3: attention v4 — LDS-free, packed row pairs ----------------
// block (h,b), 192 threads, lanes 0..171 own row pair (2l, 2l+1).
// k/v read at wave-uniform address (s_load-eligible); all math v_pk_fma_f32.
__global__ __launch_bounds__(192) void attn_kernel(const float* __restrict__ ws,
                                                   const float* __restrict__ bT,
                                                   const float* __restrict__ vf,
                                                   float* __restrict__ ao) {
    const int h = blockIdx.x, b = blockIdx.y;
    const int l = threadIdx.x;
    if (l >= 172) return;                      // no barriers in kernel -> early exit safe
    const size_t off = ((size_t)b * H_HEADS + h) * CH_STR;
    const float4* __restrict__ K1 = (const float4*)(ws + 1 * AP + off);
    const float4* __restrict__ K2 = (const float4*)(ws + 3 * AP + off);
    const float4* __restrict__ Vv = (const float4*)(vf + off);
    const float*  __restrict__ Q1 = ws + 0 * AP + off;
    const float*  __restrict__ Q2 = ws + 2 * AP + off;
    const int rA = l * 2, rB = rA + 1;         // rA <= 342; rB == 343 only at l=171 (pad)
    const float4 q1a = *(const float4*)&Q1[rA * 4];
    const float4 q1b = *(const float4*)&Q1[rB * 4];
    const float4 q2a = *(const float4*)&Q2[rA * 4];
    const float4 q2b = *(const float4*)&Q2[rB * 4];
    const v2f q1p0 = {q1a.x, q1b.x}, q1p1 = {q1a.y, q1b.y},
              q1p2 = {q1a.z, q1b.z}, q1p3 = {q1a.w, q1b.w};
    const v2f q2p0 = {q2a.x, q2b.x}, q2p1 = {q2a.y, q2b.y},
              q2p2 = {q2a.z, q2b.z}, q2p3 = {q2a.w, q2b.w};
    const float* bP = bT + (size_t)h * N_TOK * N_PAD + rA;
    v2f sum2 = {0.f, 0.f};
    v2f a0 = {0.f, 0.f}, a1 = {0.f, 0.f}, a2 = {0.f, 0.f}, a3 = {0.f, 0.f};
    #pragma unroll 4
    for (int j = 0; j < N_TOK; ++j) {
        const float4 k1 = K1[j];               // uniform address -> scalar/broadcast load
        const float4 k2 = K2[j];
        const float4 v  = Vv[j];
        v2f s2 = *(const v2f*)(bP + (size_t)j * N_PAD);   // {bias[j][rA], bias[j][rB]}
        s2 = FMA2((v2f)(k1.x), q1p0, s2); s2 = FMA2((v2f)(k1.y), q1p1, s2);
        s2 = FMA2((v2f)(k1.z), q1p2, s2); s2 = FMA2((v2f)(k1.w), q1p3, s2);
        s2 = FMA2((v2f)(k2.x), q2p0, s2); s2 = FMA2((v2f)(k2.y), q2p1, s2);
        s2 = FMA2((v2f)(k2.z), q2p2, s2); s2 = FMA2((v2f)(k2.w), q2p3, s2);
        const v2f p2 = {exp2f(s2.x), exp2f(s2.y)};
        sum2 += p2;
        a0 = FMA2(p2, (v2f)(v.x), a0); a1 = FMA2(p2, (v2f)(v.y), a1);
        a2 = FMA2(p2, (v2f)(v.z), a2); a3 = FMA2(p2, (v2f)(v.w), a3);
    }
    {
        const float inv = 1.f / sum2.x;
        float* op = ao + ((size_t)b * N_TOK + rA) * C_DIM + h * HD;
        *(float4*)op = make_float4(a0.x * inv, a1.x * inv, a2.x * inv, a3.x * inv);
    }
    if (rB < N_TOK) {
        const float inv = 1.f / sum2.y;
        float* op = ao + ((size_t)b * N_TOK + rB) * C_DIM + h * HD;
        *(float4*)op = make_float4(a0.y * inv, a1.y * inv, a2.y * inv, a3.y * inv);
    }
}

// fallback variant: in-kernel gather (if ws too small for biasT slot), new layout
__global__ __launch_bounds__(256) void attn_kernel_g(const float* __restrict__ ws,
                                                     const float* __restrict__ rpb,
                                                     const int* __restrict__ rel,
                                                     const float* __restrict__ vf,
                                                     float* __restrict__ ao) {
    const int h = blockIdx.x, b = blockIdx.y;
    __shared__ float k1s[J_PAD * 4], k2s[J_PAD * 4], vs[J_PAD * 4];
    __shared__ float q1s[N_PAD * 4], q2s[N_PAD * 4];
    const size_t off = ((size_t)b * H_HEADS + h) * CH_STR;
    const float* Q1 = ws + 0 * AP + off;
    const float* K1 = ws + 1 * AP + off;
    const float* Q2 = ws + 2 * AP + off;
    const float* K2 = ws + 3 * AP + off;
    const float* V  = vf + off;
    const int tid = threadIdx.x;
    for (int e = tid; e < N_PAD * 4; e += 256) {     // layout already [n][d]: direct copy
        k1s[e] = K1[e]; k2s[e] = K2[e]; vs[e] = V[e];
        q1s[e] = Q1[e]; q2s[e] = Q2[e];
    }
    for (int e = N_PAD * 4 + tid; e < J_PAD * 4; e += 256) {
        k1s[e] = 0.f; k2s[e] = 0.f; vs[e] = 0.f;
    }
    __syncthreads();
    const int wid = tid >> 6, lane = tid & 63;
    const int grp = lane >> 4, l16 = lane & 15;
    const float* rpbh = rpb + h;
    for (int t = 0; t < 22; ++t) {
        const int i = t * 16 + wid * 4 + grp;
        const int ig = min(i, N_TOK - 1);
        const float4 q1 = *(const float4*)&q1s[ig * 4];
        const float4 q2 = *(const float4*)&q2s[ig * 4];
        const int* relRow = rel + (size_t)ig * N_TOK;
        float sum = 0.f, a0 = 0.f, a1 = 0.f, a2 = 0.f, a3 = 0.f;
        #pragma unroll 4
        for (int it = 0; it < 22; ++it) {
            const int jj = it * 16 + l16;
            float s = (jj < N_TOK) ? rpbh[relRow[jj] * H_HEADS] * LOG2E : -16384.f;
            const float4 k1 = *(const float4*)&k1s[jj * 4];
            const float4 k2 = *(const float4*)&k2s[jj * 4];
            s = fmaf(q1.x, k1.x, s); s = fmaf(q1.y, k1.y, s);
            s = fmaf(q1.z, k1.z, s); s = fmaf(q1.w, k1.w, s);
            s = fmaf(q2.x, k2.x, s); s = fmaf(q2.y, k2.y, s);
            s = fmaf(q2.z, k2.z, s); s = fmaf(q2.w, k2.w, s);
            const float p = exp2f(s);
            const float4 v = *(const float4*)&vs[jj * 4];
            sum += p;
            a0 = fmaf(p, v.x, a0); a1 = fmaf(p, v.y, a1);
            a2 = fmaf(p, v.z, a2); a3 = fmaf(p, v.w, a3);
        }
        #pragma unroll
        for (int o = 8; o; o >>= 1) {
            sum += __shfl_xor(sum, o, 16);
            a0 += __shfl_xor(a0, o, 16); a1 += __shfl_xor(a1, o, 16);
            a2 += __shfl_xor(a2, o, 16); a3 += __shfl_xor(a3, o, 16);
        }
        if (l16 == 0 && i < N_TOK) {
            const float inv = 1.f / sum;
            float* op = ao + ((size_t)b * N_TOK + i) * C_DIM + h * HD;
            *(float4*)op = make_float4(a0 * inv, a1 * inv, a2 * inv, a3 * inv);
        }
    }
}

// ---------------- kernel 4: output projection (32-row tiles) -> float32 ----------------
__global__ __launch_bounds__(256) void proj_kernel(const float* __restrict__ ao,
                                                   const float* __restrict__ pw,
                                                   const float* __restrict__ pb,
                                                   float* __restrict__ out) {
    __shared__ float xs[32 * C_DIM];
    __shared__ float pwl[C_DIM * 97];
    const int b = blockIdx.y, row0 = blockIdx.x * 32;
    const int rows = min(32, N_TOK - row0);
    for (int e = threadIdx.x; e < rows * C_DIM; e += blockDim.x)
        xs[e] = ao[((size_t)b * N_TOK + row0) * C_DIM + e];
    for (int e = threadIdx.x; e < C_DIM * C_DIM; e += blockDim.x) {
        int c = e / C_DIM, k = e - c * C_DIM;
        pwl[c * 97 + k] = pw[e];
    }
    __syncthreads();
    for (int e = threadIdx.x; e < rows * C_DIM; e += blockDim.x) {
        int r = e / C_DIM, c = e - r * C_DIM;
        float acc = pb[c];
        const float* xr = xs + r * C_DIM;
        const float* wr = pwl + c * 97;
        #pragma unroll 8
        for (int k = 0; k < C_DIM; ++k) acc += xr[k] * wr[k];
        out[((size_t)b * N_TOK + row0) * C_DIM + e] = acc;
    }
}

static const void* find_by_size(void* const* d_in, const int* in_sizes, int n_in,
                                int want, int occurrence) {
    int seen = 0;
    for (int i = 0; i < n_in; ++i) {
        if (in_sizes[i] == want) {
            if (seen == occurrence) return d_in[i];
            ++seen;
        }
    }
    return nullptr;
}

extern "C" void kernel_launch(void* const* d_in, const int* in_sizes, int n_in,
                              void* d_out, int out_size, void* d_ws, size_t ws_size,
                              hipStream_t stream) {
    const float* x1     = (const float*)find_by_size(d_in, in_sizes, n_in, 1053696, 0);
    const float* x2     = (const float*)find_by_size(d_in, in_sizes, n_in, 1053696, 1);
    const float* qkv_w  = (const float*)find_by_size(d_in, in_sizes, n_in, 27648, 0);
    const float* qkv_b  = (const float*)find_by_size(d_in, in_sizes, n_in, 288, 0);
    const float* proj_w = (const float*)find_by_size(d_in, in_sizes, n_in, 9216, 0);
    const float* proj_b = (const float*)find_by_size(d_in, in_sizes, n_in, 96, 0);
    const float* rpb    = (const float*)find_by_size(d_in, in_sizes, n_in, 52728, 0);
    const float* fuse_w = (const float*)find_by_size(d_in, in_sizes, n_in, 1152, 0);
    const float* fuse_b = (const float*)find_by_size(d_in, in_sizes, n_in, 24, 0);
    const int*   rel    = (const int*)  find_by_size(d_in, in_sizes, n_in, 117649, 0);

    if (!x1 || !x2 || !qkv_w || !qkv_b || !proj_w || !proj_b || !rpb || !fuse_w ||
        !fuse_b || !rel) {
        x1     = (const float*)d_in[0];
        x2     = (const float*)d_in[1];
        qkv_w  = (const float*)d_in[2];
        qkv_b  = (const float*)d_in[3];
        proj_w = (const float*)d_in[4];
        proj_b = (const float*)d_in[5];
        rpb    = (const float*)d_in[6];
        fuse_w = (const float*)d_in[7];
        fuse_b = (const float*)d_in[8];
        rel    = (const int*)d_in[9];
    }

    float* ws = (float*)d_ws;
    float* V1 = ws + 4 * AP;
    float* V2 = ws + 5 * AP;
    float* VF = ws + 6 * AP;
    float* AO = V1;            // alias: v1 dead after fuse_kernel
    float* BIAS = ws + 7 * AP;
    float* out = (float*)d_out;
    const bool use_bias = ws_size >= (7 * AP + BT_ELEMS) * sizeof(float);

    if (use_bias)
        biasT_kernel<<<dim3(121, H_HEADS), 256, 0, stream>>>(rpb, rel, BIAS);
    qkv_kernel<<<dim3(11, 3, B_WIN), 192, 0, stream>>>(x1, x2, qkv_w, qkv_b, ws);
    fuse_kernel<<<dim3(H_HEADS, B_WIN), 256, 0, stream>>>(V1, V2, fuse_w, fuse_b, VF);
    if (use_bias)
        attn_kernel<<<dim3(H_HEADS, B_WIN), 192, 0, stream>>>(ws, BIAS, VF, AO);
    else
        attn_kernel_g<<<dim3(H_HEADS, B_WIN), 256, 0, stream>>>(ws, rpb, rel, VF, AO);
    proj_kernel<<<dim3(11, B_WIN), 256, 0, stream>>>(AO, proj_w, proj_b, out);
}

// Round 11
// 223.787 us; speedup vs baseline: 1.0879x; 1.0879x over previous
//
#include <hip/hip_runtime.h>
#include <hip/hip_bf16.h>

#define N_TOK 343
#define N_PAD 344
#define J_PAD 352
#define C_DIM 96
#define H_HEADS 24
#define HD 4
#define B_WIN 32
#define LOG2E 1.4426950408889634f
#define SCALE_Q (0.5f * LOG2E)    // attn scale folded with log2(e) for exp2-space softmax
#define EPS_IN 1e-5f
#define CH_STR (HD * N_PAD)                    // 1376 floats per (b,h)
#define AP ((size_t)B_WIN * H_HEADS * CH_STR)  // 1,056,768 floats per slot
#define BT_ELEMS ((size_t)H_HEADS * N_PAD * N_PAD)     // 2,840,064 floats (11.4 MB)
// layout of q/k/v/vf slots: [b][h][n][d] (float4 per token n), token row 343 = zero pad
// ws slots: 0=q1 1=k1 2=q2 3=k2 4=v1(->AO) 5=v2 6=vf [7: biasT if ws_size allows]

typedef float v2f __attribute__((ext_vector_type(2)));
#define FMA2(a, b, c) __builtin_elementwise_fma(a, b, c)

// ---------------- kernel 0: transposed bias: bT[h][j][i] = rpb[rel[i,j]*H+h]*log2e ----------------
// j and i padded to 344; pad entries = -16384 (exp2 -> 0)
__global__ __launch_bounds__(256) void biasT_kernel(const float* __restrict__ rpb,
                                                    const int* __restrict__ rel,
                                                    float* __restrict__ bT) {
    const int h = blockIdx.y;
    const int ti = blockIdx.x / 11, tj = blockIdx.x - 11 * (blockIdx.x / 11);
    const int i0 = ti * 32, j0 = tj * 32;
    __shared__ float tile[32][33];
    const int tid = threadIdx.x;
    for (int e = tid; e < 1024; e += 256) {
        int r = e >> 5, c = e & 31;            // r=i-local, c=j-local (coalesced over j)
        int i = i0 + r, j = j0 + c;
        float v = -16384.f;
        if (i < N_TOK && j < N_TOK) v = rpb[rel[i * N_TOK + j] * H_HEADS + h] * LOG2E;
        tile[r][c] = v;
    }
    __syncthreads();
    for (int e = tid; e < 1024; e += 256) {
        int c = e >> 5, r = e & 31;            // writes coalesced over i
        int i = i0 + r, j = j0 + c;
        if (i < N_PAD && j < N_PAD)
            bT[((size_t)h * N_PAD + j) * N_PAD + i] = tile[r][c];
    }
}

// ---------------- kernel 1: QKV projection, LDS-tiled GEMM ----------------
__global__ __launch_bounds__(192) void qkv_kernel(const float* __restrict__ x1,
                                                  const float* __restrict__ x2,
                                                  const float* __restrict__ w,
                                                  const float* __restrict__ bqkv,
                                                  float* __restrict__ ws) {
    __shared__ float wt[96 * 100];
    __shared__ float xs[2][32 * 97];
    const int s = blockIdx.y, b = blockIdx.z, r0 = blockIdx.x * 32;
    const int rows = min(32, N_TOK - r0);
    const int tid = threadIdx.x;
    for (int e = tid; e < 96 * 96; e += 192) {
        int j = e / 96, k = e - j * 96;
        wt[k * 100 + j] = w[s * 96 * 96 + e];
    }
    const float* x1p = x1 + ((size_t)b * N_TOK + r0) * C_DIM;
    const float* x2p = x2 + ((size_t)b * N_TOK + r0) * C_DIM;
    for (int e = tid; e < rows * 96; e += 192) {
        int r = e / 96, k = e - r * 96;
        xs[0][r * 97 + k] = x1p[e];
        xs[1][r * 97 + k] = x2p[e];
    }
    __syncthreads();
    const int rg = tid & 7, og = tid >> 3;   // og = head (0..23), rg = row group (0..7)
    const int oc0 = og * 4, rr = rg * 4;
    float acc[2][4][4];
    #pragma unroll
    for (int i = 0; i < 4; ++i) {
        float bv = bqkv[s * 96 + oc0 + i];
        #pragma unroll
        for (int src = 0; src < 2; ++src)
            #pragma unroll
            for (int j = 0; j < 4; ++j) acc[src][i][j] = bv;
    }
    for (int k = 0; k < 96; ++k) {
        float4 w4 = *(const float4*)&wt[k * 100 + oc0];
        float wv[4] = {w4.x, w4.y, w4.z, w4.w};
        float xv0[4], xv1[4];
        #pragma unroll
        for (int j = 0; j < 4; ++j) {
            xv0[j] = xs[0][(rr + j) * 97 + k];
            xv1[j] = xs[1][(rr + j) * 97 + k];
        }
        #pragma unroll
        for (int i = 0; i < 4; ++i)
            #pragma unroll
            for (int j = 0; j < 4; ++j) {
                acc[0][i][j] += xv0[j] * wv[i];
                acc[1][i][j] += xv1[j] * wv[i];
            }
    }
    const float scl = (s == 0) ? SCALE_Q : 1.0f;
    // store layout: [b][h=og][row][d]; row 343 (=N_TOK) is the pad row -> zeros
    #pragma unroll
    for (int j = 0; j < 4; ++j) {
        int row = r0 + rr + j;
        if (row > N_TOK) continue;
        size_t base = (((size_t)b * H_HEADS + og) * N_PAD + row) * 4;
        #pragma unroll
        for (int src = 0; src < 2; ++src) {
            int slot = (s == 0) ? (src ? 2 : 0) : (s == 1) ? (src ? 3 : 1) : (src ? 5 : 4);
            float4 val = (row == N_TOK)
                ? make_float4(0.f, 0.f, 0.f, 0.f)
                : make_float4(acc[src][0][j] * scl, acc[src][1][j] * scl,
                              acc[src][2][j] * scl, acc[src][3][j] * scl);
            *(float4*)(ws + (size_t)slot * AP + base) = val;
        }
    }
}

// ---------------- kernel 2: fuse (1x1 conv 48->24 + InstanceNorm + relu + sigmoid) ----------------
__global__ __launch_bounds__(256) void fuse_kernel(const float* __restrict__ v1,
                                                   const float* __restrict__ v2,
                                                   const float* __restrict__ fw,
                                                   const float* __restrict__ fb,
                                                   float* __restrict__ vf) {
    const int o = blockIdx.x, b = blockIdx.y;
    __shared__ float ts[N_TOK * HD];
    __shared__ float red[32];
    __shared__ float fwl[48];
    if (threadIdx.x < 48) fwl[threadIdx.x] = fw[o * 48 + threadIdx.x];
    __syncthreads();
    const float bo = fb[o];
    const float* p1 = v1 + (size_t)b * H_HEADS * CH_STR;
    const float* p2 = v2 + (size_t)b * H_HEADS * CH_STR;
    float lsum = 0.f, lsq = 0.f;
    for (int e = threadIdx.x; e < N_TOK * HD; e += blockDim.x) {
        float acc = bo;                        // e = n*4+d matches [n][d] layout directly
        #pragma unroll
        for (int c = 0; c < H_HEADS; ++c) {
            acc += fwl[c]      * p1[(size_t)c * CH_STR + e];
            acc += fwl[24 + c] * p2[(size_t)c * CH_STR + e];
        }
        ts[e] = acc;
        lsum += acc; lsq += acc * acc;
    }
    for (int off = 32; off; off >>= 1) {
        lsum += __shfl_xor(lsum, off);
        lsq  += __shfl_xor(lsq, off);
    }
    int wid = threadIdx.x >> 6, lane = threadIdx.x & 63;
    if (lane == 0) { red[wid] = lsum; red[8 + wid] = lsq; }
    __syncthreads();
    if (threadIdx.x == 0) {
        float su = red[0] + red[1] + red[2] + red[3];
        float q  = red[8] + red[9] + red[10] + red[11];
        float mean = su / (float)(N_TOK * HD);
        float var  = q / (float)(N_TOK * HD) - mean * mean;
        red[16] = mean;
        red[17] = rsqrtf(var + EPS_IN);
    }
    __syncthreads();
    const float mean = red[16], inv = red[17];
    float* outp = vf + ((size_t)b * H_HEADS + o) * CH_STR;
    for (int e = threadIdx.x; e < N_TOK * HD; e += blockDim.x) {
        float x = (ts[e] - mean) * inv;
        x = fmaxf(x, 0.f);
        outp[e] = 1.f / (1.f + __expf(-x));
    }
}

// ---------------- kernel 3: attention v5 — LDS-free, packed row pairs, SW-pipelined ----------------
// block (h,b), 192 threads, lanes 0..171 own row pair (2l, 2l+1).
// j-loop: 344 = 43 x 8, two named register batches (A/B), loads issued a full
// batch-compute ahead of use (T14 issue-early/consume-late; static indexing only).
struct JBatch {
    v2f bv[4];
    float4 k1[4], k2[4], vv[4];
};

#define LOAD_BATCH(B_, j0_)                                            \
    _Pragma("unroll")                                                  \
    for (int u = 0; u < 4; ++u) {                                      \
        B_.bv[u] = *(const v2f*)(bP + (size_t)((j0_) + u) * N_PAD);    \
        B_.k1[u] = K1[(j0_) + u];                                      \
        B_.k2[u] = K2[(j0_) + u];                                      \
        B_.vv[u] = Vv[(j0_) + u];                                      \
    }

#define COMP_BATCH(B_)                                                 \
    _Pragma("unroll")                                                  \
    for (int u = 0; u < 4; ++u) {                                      \
        const float4 k1 = B_.k1[u], k2 = B_.k2[u], v = B_.vv[u];       \
        v2f s2 = B_.bv[u];                                             \
        s2 = FMA2((v2f)(k1.x), q1p0, s2); s2 = FMA2((v2f)(k1.y), q1p1, s2); \
        s2 = FMA2((v2f)(k1.z), q1p2, s2); s2 = FMA2((v2f)(k1.w), q1p3, s2); \
        s2 = FMA2((v2f)(k2.x), q2p0, s2); s2 = FMA2((v2f)(k2.y), q2p1, s2); \
        s2 = FMA2((v2f)(k2.z), q2p2, s2); s2 = FMA2((v2f)(k2.w), q2p3, s2); \
        const v2f p2 = {exp2f(s2.x), exp2f(s2.y)};                     \
        sum2 += p2;                                                    \
        a0 = FMA2(p2, (v2f)(v.x), a0); a1 = FMA2(p2, (v2f)(v.y), a1);  \
        a2 = FMA2(p2, (v2f)(v.z), a2); a3 = FMA2(p2, (v2f)(v.w), a3);  \
    }

__global__ __launch_bounds__(192) void attn_kernel(const float* __restrict__ ws,
                                                   const float* __restrict__ bT,
                                                   const float* __restrict__ vf,
                                                   float* __restrict__ ao) {
    const int h = blockIdx.x, b = blockIdx.y;
    const int l = threadIdx.x;
    if (l >= 172) return;                      // no barriers in kernel -> early exit safe
    const size_t off = ((size_t)b * H_HEADS + h) * CH_STR;
    const float4* __restrict__ K1 = (const float4*)(ws + 1 * AP + off);
    const float4* __restrict__ K2 = (const float4*)(ws + 3 * AP + off);
    const float4* __restrict__ Vv = (const float4*)(vf + off);
    const float*  __restrict__ Q1 = ws + 0 * AP + off;
    const float*  __restrict__ Q2 = ws + 2 * AP + off;
    const int rA = l * 2, rB = rA + 1;         // rB == 343 only at l=171 (pad row, q=0)
    const float4 q1a = *(const float4*)&Q1[rA * 4];
    const float4 q1b = *(const float4*)&Q1[rB * 4];
    const float4 q2a = *(const float4*)&Q2[rA * 4];
    const float4 q2b = *(const float4*)&Q2[rB * 4];
    const v2f q1p0 = {q1a.x, q1b.x}, q1p1 = {q1a.y, q1b.y},
              q1p2 = {q1a.z, q1b.z}, q1p3 = {q1a.w, q1b.w};
    const v2f q2p0 = {q2a.x, q2b.x}, q2p1 = {q2a.y, q2b.y},
              q2p2 = {q2a.z, q2b.z}, q2p3 = {q2a.w, q2b.w};
    const float* bP = bT + (size_t)h * N_PAD * N_PAD + rA;
    v2f sum2 = {0.f, 0.f};
    v2f a0 = {0.f, 0.f}, a1 = {0.f, 0.f}, a2 = {0.f, 0.f}, a3 = {0.f, 0.f};

    JBatch A, B;
    LOAD_BATCH(A, 0)
    LOAD_BATCH(B, 4)
    for (int t = 0; t < 43; ++t) {
        const int j0 = t * 8;
        COMP_BATCH(A)
        if (t < 42) { LOAD_BATCH(A, j0 + 8) }     // in flight across COMP_BATCH(B)
        COMP_BATCH(B)
        if (t < 42) { LOAD_BATCH(B, j0 + 12) }    // in flight across next COMP_BATCH(A)
    }
    {
        const float inv = 1.f / sum2.x;
        float* op = ao + ((size_t)b * N_TOK + rA) * C_DIM + h * HD;
        *(float4*)op = make_float4(a0.x * inv, a1.x * inv, a2.x * inv, a3.x * inv);
    }
    if (rB < N_TOK) {
        const float inv = 1.f / sum2.y;
        float* op = ao + ((size_t)b * N_TOK + rB) * C_DIM + h * HD;
        *(float4*)op = make_float4(a0.y * inv, a1.y * inv, a2.y * inv, a3.y * inv);
    }
}

// fallback variant: in-kernel gather (if ws too small for biasT slot), [n][d] layout
__global__ __launch_bounds__(256) void attn_kernel_g(const float* __restrict__ ws,
                                                     const float* __restrict__ rpb,
                                                     const int* __restrict__ rel,
                                                     const float* __restrict__ vf,
                                                     float* __restrict__ ao) {
    const int h = blockIdx.x, b = blockIdx.y;
    __shared__ float k1s[J_PAD * 4], k2s[J_PAD * 4], vs[J_PAD * 4];
    __shared__ float q1s[N_PAD * 4], q2s[N_PAD * 4];
    const size_t off = ((size_t)b * H_HEADS + h) * CH_STR;
    const float* Q1 = ws + 0 * AP + off;
    const float* K1 = ws + 1 * AP + off;
    const float* Q2 = ws + 2 * AP + off;
    const float* K2 = ws + 3 * AP + off;
    const float* V  = vf + off;
    const int tid = threadIdx.x;
    for (int e = tid; e < N_PAD * 4; e += 256) {
        k1s[e] = K1[e]; k2s[e] = K2[e]; vs[e] = V[e];
        q1s[e] = Q1[e]; q2s[e] = Q2[e];
    }
    for (int e = N_PAD * 4 + tid; e < J_PAD * 4; e += 256) {
        k1s[e] = 0.f; k2s[e] = 0.f; vs[e] = 0.f;
    }
    __syncthreads();
    const int wid = tid >> 6, lane = tid & 63;
    const int grp = lane >> 4, l16 = lane & 15;
    const float* rpbh = rpb + h;
    for (int t = 0; t < 22; ++t) {
        const int i = t * 16 + wid * 4 + grp;
        const int ig = min(i, N_TOK - 1);
        const float4 q1 = *(const float4*)&q1s[ig * 4];
        const float4 q2 = *(const float4*)&q2s[ig * 4];
        const int* relRow = rel + (size_t)ig * N_TOK;
        float sum = 0.f, a0 = 0.f, a1 = 0.f, a2 = 0.f, a3 = 0.f;
        #pragma unroll 4
        for (int it = 0; it < 22; ++it) {
            const int jj = it * 16 + l16;
            float s = (jj < N_TOK) ? rpbh[relRow[jj] * H_HEADS] * LOG2E : -16384.f;
            const float4 k1 = *(const float4*)&k1s[jj * 4];
            const float4 k2 = *(const float4*)&k2s[jj * 4];
            s = fmaf(q1.x, k1.x, s); s = fmaf(q1.y, k1.y, s);
            s = fmaf(q1.z, k1.z, s); s = fmaf(q1.w, k1.w, s);
            s = fmaf(q2.x, k2.x, s); s = fmaf(q2.y, k2.y, s);
            s = fmaf(q2.z, k2.z, s); s = fmaf(q2.w, k2.w, s);
            const float p = exp2f(s);
            const float4 v = *(const float4*)&vs[jj * 4];
            sum += p;
            a0 = fmaf(p, v.x, a0); a1 = fmaf(p, v.y, a1);
            a2 = fmaf(p, v.z, a2); a3 = fmaf(p, v.w, a3);
        }
        #pragma unroll
        for (int o = 8; o; o >>= 1) {
            sum += __shfl_xor(sum, o, 16);
            a0 += __shfl_xor(a0, o, 16); a1 += __shfl_xor(a1, o, 16);
            a2 += __shfl_xor(a2, o, 16); a3 += __shfl_xor(a3, o, 16);
        }
        if (l16 == 0 && i < N_TOK) {
            const float inv = 1.f / sum;
            float* op = ao + ((size_t)b * N_TOK + i) * C_DIM + h * HD;
            *(float4*)op = make_float4(a0 * inv, a1 * inv, a2 * inv, a3 * inv);
        }
    }
}

// ---------------- kernel 4: output projection (32-row tiles) -> float32 ----------------
__global__ __launch_bounds__(256) void proj_kernel(const float* __restrict__ ao,
                                                   const float* __restrict__ pw,
                                                   const float* __restrict__ pb,
                                                   float* __restrict__ out) {
    __shared__ float xs[32 * C_DIM];
    __shared__ float pwl[C_DIM * 97];
    const int b = blockIdx.y, row0 = blockIdx.x * 32;
    const int rows = min(32, N_TOK - row0);
    for (int e = threadIdx.x; e < rows * C_DIM; e += blockDim.x)
        xs[e] = ao[((size_t)b * N_TOK + row0) * C_DIM + e];
    for (int e = threadIdx.x; e < C_DIM * C_DIM; e += blockDim.x) {
        int c = e / C_DIM, k = e - c * C_DIM;
        pwl[c * 97 + k] = pw[e];
    }
    __syncthreads();
    for (int e = threadIdx.x; e < rows * C_DIM; e += blockDim.x) {
        int r = e / C_DIM, c = e - r * C_DIM;
        float acc = pb[c];
        const float* xr = xs + r * C_DIM;
        const float* wr = pwl + c * 97;
        #pragma unroll 8
        for (int k = 0; k < C_DIM; ++k) acc += xr[k] * wr[k];
        out[((size_t)b * N_TOK + row0) * C_DIM + e] = acc;
    }
}

static const void* find_by_size(void* const* d_in, const int* in_sizes, int n_in,
                                int want, int occurrence) {
    int seen = 0;
    for (int i = 0; i < n_in; ++i) {
        if (in_sizes[i] == want) {
            if (seen == occurrence) return d_in[i];
            ++seen;
        }
    }
    return nullptr;
}

extern "C" void kernel_launch(void* const* d_in, const int* in_sizes, int n_in,
                              void* d_out, int out_size, void* d_ws, size_t ws_size,
                              hipStream_t stream) {
    const float* x1     = (const float*)find_by_size(d_in, in_sizes, n_in, 1053696, 0);
    const float* x2     = (const float*)find_by_size(d_in, in_sizes, n_in, 1053696, 1);
    const float* qkv_w  = (const float*)find_by_size(d_in, in_sizes, n_in, 27648, 0);
    const float* qkv_b  = (const float*)find_by_size(d_in, in_sizes, n_in, 288, 0);
    const float* proj_w = (const float*)find_by_size(d_in, in_sizes, n_in, 9216, 0);
    const float* proj_b = (const float*)find_by_size(d_in, in_sizes, n_in, 96, 0);
    const float* rpb    = (const float*)find_by_size(d_in, in_sizes, n_in, 52728, 0);
    const float* fuse_w = (const float*)find_by_size(d_in, in_sizes, n_in, 1152, 0);
    const float* fuse_b = (const float*)find_by_size(d_in, in_sizes, n_in, 24, 0);
    const int*   rel    = (const int*)  find_by_size(d_in, in_sizes, n_in, 117649, 0);

    if (!x1 || !x2 || !qkv_w || !qkv_b || !proj_w || !proj_b || !rpb || !fuse_w ||
        !fuse_b || !rel) {
        x1     = (const float*)d_in[0];
        x2     = (const float*)d_in[1];
        qkv_w  = (const float*)d_in[2];
        qkv_b  = (const float*)d_in[3];
        proj_w = (const float*)d_in[4];
        proj_b = (const float*)d_in[5];
        rpb    = (const float*)d_in[6];
        fuse_w = (const float*)d_in[7];
        fuse_b = (const float*)d_in[8];
        rel    = (const int*)d_in[9];
    }

    float* ws = (float*)d_ws;
    float* V1 = ws + 4 * AP;
    float* V2 = ws + 5 * AP;
    float* VF = ws + 6 * AP;
    float* AO = V1;            // alias: v1 dead after fuse_kernel
    float* BIAS = ws + 7 * AP;
    float* out = (float*)d_out;
    const bool use_bias = ws_size >= (7 * AP + BT_ELEMS) * sizeof(float);

    if (use_bias)
        biasT_kernel<<<dim3(121, H_HEADS), 256, 0, stream>>>(rpb, rel, BIAS);
    qkv_kernel<<<dim3(11, 3, B_WIN), 192, 0, stream>>>(x1, x2, qkv_w, qkv_b, ws);
    fuse_kernel<<<dim3(H_HEADS, B_WIN), 256, 0, stream>>>(V1, V2, fuse_w, fuse_b, VF);
    if (use_bias)
        attn_kernel<<<dim3(H_HEADS, B_WIN), 192, 0, stream>>>(ws, BIAS, VF, AO);
    else
        attn_kernel_g<<<dim3(H_HEADS, B_WIN), 256, 0, stream>>>(ws, rpb, rel, VF, AO);
    proj_kernel<<<dim3(11, B_WIN), 256, 0, stream>>>(AO, proj_w, proj_b, out);
}